// Round 3
// baseline (1028.480 us; speedup 1.0000x reference)
//
#include <hip/hip_runtime.h>

// CTRNN forward, B=256 T=2048 D=32 H=64. ALL tensors fp32.
// r6: single fused kernel (xproj folded into the recurrence), grid 256x64.
//  - r5 post-mortem: ds_swizzle broadcast 919cy/step (LDS latency unhidden at
//    1 wave/SIMD). Reverted. r4 readlane+vfma2 was 569cy/step: issue-bound,
//    ~64 v_mov building v2f pairs from SGPRs were half the matvec cost.
//  - Matvec now: 64 v_readlane + 64 v_fmac_f32 with the broadcast value as a
//    DIRECT SGPR operand (inline asm "s" constraint -> no movs). Accumulation
//    order identical to the passing r4 kernel: s0..s3 by col mod 4,
//    sum = ((s0+s2)+(s1+s3)) + xp.
//  - xproj fused: xp[t] = dot(x[b][t][:], W_in[lane]) computed in-loop from a
//    4-deep register ring of x rows (8x float4 wave-uniform loads issued 4
//    steps ahead, ~1000cy prefetch > 900cy HBM latency). Same pairing as the
//    passing r5 xproj -> bit-identical xp. Deletes the xproj kernel and the
//    128MB xp write + 128MB re-read.

#define Bb 256
#define Tt 2048
#define Dd 32
#define Hh 64

typedef float v2f __attribute__((ext_vector_type(2)));

static constexpr float ALPHA = (float)(16.67 / 40.0);
static constexpr float OMA   = 1.0f - ALPHA;

static __device__ inline v2f vfma2(v2f a, v2f b, v2f c) {
#if __has_builtin(__builtin_elementwise_fma)
    return __builtin_elementwise_fma(a, b, c);
#else
    v2f r; r.x = fmaf(a.x, b.x, c.x); r.y = fmaf(a.y, b.y, c.y); return r;
#endif
}

// 4 columns of the recurrence matvec: readlane -> SGPR -> v_fmac (no movs).
// Col k accumulates into s(k&3); w4[k>>2] component (k&3) is the W column coeff.
#define MV4(k0)                                                               \
    {                                                                         \
        const float h0 = __int_as_float(__builtin_amdgcn_readlane(hb, (k0) + 0)); \
        const float h1 = __int_as_float(__builtin_amdgcn_readlane(hb, (k0) + 1)); \
        const float h2 = __int_as_float(__builtin_amdgcn_readlane(hb, (k0) + 2)); \
        const float h3 = __int_as_float(__builtin_amdgcn_readlane(hb, (k0) + 3)); \
        asm("v_fmac_f32 %0, %1, %2" : "+v"(s0) : "s"(h0), "v"(w4[(k0) >> 2].x)); \
        asm("v_fmac_f32 %0, %1, %2" : "+v"(s1) : "s"(h1), "v"(w4[(k0) >> 2].y)); \
        asm("v_fmac_f32 %0, %1, %2" : "+v"(s2) : "s"(h2), "v"(w4[(k0) >> 2].z)); \
        asm("v_fmac_f32 %0, %1, %2" : "+v"(s3) : "s"(h3), "v"(w4[(k0) >> 2].w)); \
    }

// One recurrence step at time tcur:
//   - issue 8 float4 loads of x row (tcur+4) into BUFL (4-deep ring)
//   - matvec over hold (h_{t-1}) via readlane/fmac
//   - compute XPN = xp for row tcur+1 from BUFN (loads landed 3 steps ago)
//   - finish h_t, store, advance
#define STEP(tcur, BUFL, BUFN, XPC, XPN)                                      \
    {                                                                         \
        {                                                                     \
            int rr = (tcur) + 4; rr = rr < Tt ? rr : (Tt - 1);                \
            const float4* xr4 = reinterpret_cast<const float4*>(              \
                xrow + (size_t)rr * Dd);                                      \
            _Pragma("unroll")                                                 \
            for (int j = 0; j < 8; ++j) BUFL[j] = xr4[j];                     \
        }                                                                     \
        const int hb = __float_as_int(hold);                                  \
        float s0 = 0.f, s1 = 0.f, s2 = 0.f, s3 = 0.f;                         \
        MV4(0)  MV4(4)  MV4(8)  MV4(12) MV4(16) MV4(20) MV4(24) MV4(28)      \
        MV4(32) MV4(36) MV4(40) MV4(44) MV4(48) MV4(52) MV4(56) MV4(60)      \
        {                                                                     \
            v2f a01 = {0.f, 0.f}, a23 = {0.f, 0.f};                           \
            _Pragma("unroll")                                                 \
            for (int j = 0; j < 8; ++j) {                                     \
                const float4 x4 = BUFN[j];                                    \
                const v2f xlo = {x4.x, x4.y};                                 \
                const v2f xhi = {x4.z, x4.w};                                 \
                a01 = vfma2(wiv[2 * j + 0], xlo, a01);                        \
                a23 = vfma2(wiv[2 * j + 1], xhi, a23);                        \
            }                                                                 \
            XPN = (a01.x + a01.y) + (a23.x + a23.y);                          \
        }                                                                     \
        const float sum  = ((s0 + s2) + (s1 + s3)) + XPC;                     \
        const float hnew = fmaxf(fmaf(ALPHA, sum, fmaf(OMA, hold, cb)), 0.0f);\
        *op = hnew;                                                           \
        op += Hh;                                                             \
        hold = hnew;                                                          \
    }

__global__ __launch_bounds__(64, 1) void ctrnn_fused(
    const float* __restrict__ x,
    const float* __restrict__ W_in,
    const float* __restrict__ b_in,
    const float* __restrict__ W_hh,
    const float* __restrict__ b_hh,
    float* __restrict__ out)
{
    const int b    = blockIdx.x;
    const int lane = threadIdx.x;

    // W_hh row of this lane: 64 floats as 16 float4 (static component access)
    float4 w4[16];
    const float4* wr = reinterpret_cast<const float4*>(W_hh + lane * Hh);
#pragma unroll
    for (int j = 0; j < 16; ++j) w4[j] = wr[j];

    // W_in row of this lane: 32 floats as 16 v2f (same pairing as r5 xproj)
    v2f wiv[16];
    const v2f* wir = reinterpret_cast<const v2f*>(W_in + lane * Dd);
#pragma unroll
    for (int j = 0; j < 16; ++j) wiv[j] = wir[j];

    const float cb = ALPHA * (b_in[lane] + b_hh[lane]);

    const float* xrow = x + (size_t)b * Tt * Dd;
    float*       op   = out + (size_t)b * Tt * Hh + lane;

    // x-row ring: slot k holds rows == k (mod 4)
    float4 xbA[8], xbB[8], xbC[8], xbD[8];
#pragma unroll
    for (int j = 0; j < 8; ++j) {
        xbA[j] = reinterpret_cast<const float4*>(xrow + 0 * Dd)[j];
        xbB[j] = reinterpret_cast<const float4*>(xrow + 1 * Dd)[j];
        xbC[j] = reinterpret_cast<const float4*>(xrow + 2 * Dd)[j];
        xbD[j] = reinterpret_cast<const float4*>(xrow + 3 * Dd)[j];
    }

    float xp0, xp1, xp2, xp3;
    {   // xp for row 0 (same op order as the in-loop version)
        v2f a01 = {0.f, 0.f}, a23 = {0.f, 0.f};
#pragma unroll
        for (int j = 0; j < 8; ++j) {
            const float4 x4 = xbA[j];
            const v2f xlo = {x4.x, x4.y};
            const v2f xhi = {x4.z, x4.w};
            a01 = vfma2(wiv[2 * j + 0], xlo, a01);
            a23 = vfma2(wiv[2 * j + 1], xhi, a23);
        }
        xp0 = (a01.x + a01.y) + (a23.x + a23.y);
    }

    float hold = 0.0f;
    for (int t = 0; t < Tt; t += 4) {
        STEP(t + 0, xbA, xbB, xp0, xp1)
        STEP(t + 1, xbB, xbC, xp1, xp2)
        STEP(t + 2, xbC, xbD, xp2, xp3)
        STEP(t + 3, xbD, xbA, xp3, xp0)
    }

    // h_last
    out[(size_t)Bb * Tt * Hh + (size_t)b * Hh + lane] = hold;
}

extern "C" void kernel_launch(void* const* d_in, const int* in_sizes, int n_in,
                              void* d_out, int out_size, void* d_ws, size_t ws_size,
                              hipStream_t stream) {
    const float* x    = (const float*)d_in[0];
    // d_in[1] = seq_lengths (int32): forward value is mask-independent.
    const float* W_in = (const float*)d_in[2];
    const float* b_in = (const float*)d_in[3];
    const float* W_hh = (const float*)d_in[4];
    const float* b_hh = (const float*)d_in[5];
    float* out = (float*)d_out;

    ctrnn_fused<<<dim3(Bb), dim3(64), 0, stream>>>(x, W_in, b_in, W_hh, b_hh, out);
}

// Round 4
// 664.762 us; speedup vs baseline: 1.5471x; 1.5471x over previous
//
#include <hip/hip_runtime.h>

// CTRNN forward, B=256 T=2048 D=32 H=64. ALL tensors fp32.
// r7 = r4(two-kernel, 677us) with ONE isolated change in recur:
//  - r3-fused post-mortem: 1052cy/step, VALUBusy 66%-of-SIMD => ~350 VALU/step.
//    SGPR=112 shows x loads were scalar-promoted; inline-asm fmac pinned the
//    schedule. Fusion reverted entirely.
//  - r4 recur (569cy/step): vfma2 with lane-pair broadcast forced ~64 v_mov
//    per step building v2f from readlane SGPRs. Fix: scalar readlane + fmaf
//    => compiler emits v_fmac_f32 vAcc, sH, vW (SGPR src0, no movs, no asm).
//    Matvec = 64 readlane + 64 fmac = 128 VALU (~256cy issue).
//  - Accumulation bit-identical to all passing kernels: col k -> s(k&3),
//    ascending k, sum = ((s0+s2)+(s1+s3)) + xp, same hnew formula.
// xproj: unchanged r5 version (16KB tile, pk_fma, bit-identical xp).

#define Bb 256
#define Tt 2048
#define Dd 32
#define Hh 64

typedef float v2f __attribute__((ext_vector_type(2)));

static constexpr float ALPHA = (float)(16.67 / 40.0);
static constexpr float OMA   = 1.0f - ALPHA;

static __device__ inline v2f vfma2(v2f a, v2f b, v2f c) {
#if __has_builtin(__builtin_elementwise_fma)
    return __builtin_elementwise_fma(a, b, c);
#else
    v2f r; r.x = fmaf(a.x, b.x, c.x); r.y = fmaf(a.y, b.y, c.y); return r;
#endif
}

// ---------------- Phase A: out[b][t][h] = dot(x[b][t][:], W_in[h][:]) -------
// grid 4096 = 256 b x 16 tiles(128 rows), block 256 (4 waves, 32 rows each).
// 16KB x-tile staged coalesced into LDS; per-row reads are b128 broadcasts;
// stores coalesced. Accumulation order identical to all passing kernels:
// a01.x=s0, a01.y=s1, a23.x=s2, a23.y=s3; (s0+s1)+(s2+s3).
__global__ __launch_bounds__(256) void ctrnn_xproj(
    const float* __restrict__ x,
    const float* __restrict__ W_in,
    float* __restrict__ out)
{
    __shared__ alignas(16) float xs[128 * Dd];   // 16 KB
    const int tid  = threadIdx.x;
    const int lane = tid & 63;
    const int wave = tid >> 6;
    const int b    = blockIdx.x >> 4;
    const int tile = blockIdx.x & 15;
    const int t0   = tile * 128;

    // coalesced stage: 4096 floats = 1024 float4 = 4 rounds x 256 threads
    const float4* xsrc = reinterpret_cast<const float4*>(
        x + (size_t)b * Tt * Dd + (size_t)t0 * Dd);
    float4* xdst = reinterpret_cast<float4*>(xs);
#pragma unroll
    for (int r = 0; r < 4; ++r) xdst[r * 256 + tid] = xsrc[r * 256 + tid];

    // W row per lane as v2f pairs: w2[k] = W_in[lane][2k..2k+1]
    v2f w[16];
    const v2f* wrow = reinterpret_cast<const v2f*>(W_in + lane * Dd);
#pragma unroll
    for (int j = 0; j < 16; ++j) w[j] = wrow[j];

    __syncthreads();

    float* ob = out + (size_t)b * Tt * Hh + (size_t)t0 * Hh;
    const int lt0 = wave * 32;
#pragma unroll 2
    for (int i = 0; i < 32; ++i) {
        const float4* xr = reinterpret_cast<const float4*>(xs + (lt0 + i) * Dd);
        v2f a01 = {0.f, 0.f}, a23 = {0.f, 0.f};
#pragma unroll
        for (int j = 0; j < 8; ++j) {
            const float4 xv = xr[j];
            const v2f x01 = {xv.x, xv.y};
            const v2f x23 = {xv.z, xv.w};
            a01 = vfma2(w[2 * j + 0], x01, a01);   // elements 4j, 4j+1
            a23 = vfma2(w[2 * j + 1], x23, a23);   // elements 4j+2, 4j+3
        }
        ob[(size_t)(lt0 + i) * Hh + lane] = (a01.x + a01.y) + (a23.x + a23.y);
    }
}

// ---------------- Phase B: sequential recurrence, 1 wave per batch ----------
// h state: lane k holds h[k] ("hold"). Broadcast via v_readlane -> SGPR,
// consumed DIRECTLY as v_fmac_f32 SGPR operand (scalar fmaf, no vector
// building, no asm). xp read from out rows (written by phase A), 8-deep
// register ring prefetch; row t overwritten with h_t after xp consumed.
__global__ __launch_bounds__(64) void ctrnn_recur(
    const float* __restrict__ b_in,
    const float* __restrict__ W_hh,
    const float* __restrict__ b_hh,
    float* __restrict__ out)
{
    const int b    = blockIdx.x;
    const int lane = threadIdx.x;

    // W_hh row of this lane: 64 floats as 16 float4.
    // w4[k].{x,y,z,w} = W_hh[lane][4k..4k+3]
    float4 w4[16];
    const float4* wr = reinterpret_cast<const float4*>(W_hh + lane * Hh);
#pragma unroll
    for (int j = 0; j < 16; ++j) w4[j] = wr[j];

    const float cb = ALPHA * (b_in[lane] + b_hh[lane]);

    float* ob = out + (size_t)b * Tt * Hh + lane;

    float xp[8];
#pragma unroll
    for (int j = 0; j < 8; ++j) xp[j] = ob[(size_t)j * Hh];

    float* op       = ob;                   // store ptr (row t)
    const float* lp = ob + 8 * (size_t)Hh;  // refill ptr (row t+8)

    float hold = 0.0f;
    for (int t = 0; t < Tt; t += 8) {
#pragma unroll
        for (int j = 0; j < 8; ++j) {
            const int hb = __float_as_int(hold);
            float s0 = 0.f, s1 = 0.f, s2 = 0.f, s3 = 0.f;
#pragma unroll
            for (int k = 0; k < 16; ++k) {
                const float h0 = __int_as_float(__builtin_amdgcn_readlane(hb, 4 * k + 0));
                const float h1 = __int_as_float(__builtin_amdgcn_readlane(hb, 4 * k + 1));
                const float h2 = __int_as_float(__builtin_amdgcn_readlane(hb, 4 * k + 2));
                const float h3 = __int_as_float(__builtin_amdgcn_readlane(hb, 4 * k + 3));
                s0 = fmaf(w4[k].x, h0, s0);   // cols 4k
                s1 = fmaf(w4[k].y, h1, s1);   // cols 4k+1
                s2 = fmaf(w4[k].z, h2, s2);   // cols 4k+2
                s3 = fmaf(w4[k].w, h3, s3);   // cols 4k+3
            }
            const float sum  = ((s0 + s2) + (s1 + s3)) + xp[j];
            const float hnew = fmaxf(fmaf(ALPHA, sum, fmaf(OMA, hold, cb)), 0.0f);

            *op = hnew;                    // overwrite xp row t+j with h
            op += Hh;
            hold = hnew;

            // refill ring 8 ahead (in-bounds past Tt: lands in hlast region,
            // value never consumed)
            xp[j] = *lp;
            lp += Hh;
        }
    }
    // h_last
    out[(size_t)Bb * Tt * Hh + (size_t)b * Hh + lane] = hold;
}

extern "C" void kernel_launch(void* const* d_in, const int* in_sizes, int n_in,
                              void* d_out, int out_size, void* d_ws, size_t ws_size,
                              hipStream_t stream) {
    const float* x    = (const float*)d_in[0];
    // d_in[1] = seq_lengths (int32): forward value is mask-independent.
    const float* W_in = (const float*)d_in[2];
    const float* b_in = (const float*)d_in[3];
    const float* W_hh = (const float*)d_in[4];
    const float* b_hh = (const float*)d_in[5];
    float* out = (float*)d_out;

    ctrnn_xproj<<<dim3(Bb * 16), dim3(256), 0, stream>>>(x, W_in, out);
    ctrnn_recur<<<dim3(Bb), dim3(64), 0, stream>>>(b_in, W_hh, b_hh, out);
}

// Round 5
// 572.103 us; speedup vs baseline: 1.7977x; 1.1620x over previous
//
#include <hip/hip_runtime.h>

// CTRNN forward, B=256 T=2048 D=32 H=64. ALL tensors fp32.
// r8 = r7(664us) with ONE isolated change in recur.
//  - r7 post-mortem: VALUBusy 17.9% x4 SIMD = 71.6% busy x 569cy = 407cy VALU
//    issue/step. 64*x + 76*2 = 407 -> v_readlane issues at ~4cy (quarter
//    rate). The 64 readlanes alone are 256cy/step = 63% of the step.
//  - Fix: hybrid broadcast. Columns 0..31 stay readlane+fmac (192cy, doubles
//    as the latency-fill window). Columns 32..63 move to the LDS pipe,
//    SOFTWARE-PIPELINED one iteration ahead: hs[lane]=hnew (ds_write) at end
//    of iter t, then immediately 8x ds_read_b128 broadcast of hs[32..63]
//    into q0..q7, consumed as plain VGPR fmacs in iter t+1. In-wave LDS
//    ordering (r0-proven) makes RAW safe, aliasing stops compiler reorder,
//    and the ~120cy LDS latency hides under the next iter's readlane block.
//  - Accumulation bit-identical: col k -> s(k&3), ascending cols within each
//    accumulator (0,4..28 then 32,36..60), sum = ((s0+s2)+(s1+s3)) + xp,
//    same hnew formula. absmax must stay 0.0078125.
// xproj: unchanged (passed, ~180us).

#define Bb 256
#define Tt 2048
#define Dd 32
#define Hh 64

typedef float v2f __attribute__((ext_vector_type(2)));

static constexpr float ALPHA = (float)(16.67 / 40.0);
static constexpr float OMA   = 1.0f - ALPHA;

static __device__ inline v2f vfma2(v2f a, v2f b, v2f c) {
#if __has_builtin(__builtin_elementwise_fma)
    return __builtin_elementwise_fma(a, b, c);
#else
    v2f r; r.x = fmaf(a.x, b.x, c.x); r.y = fmaf(a.y, b.y, c.y); return r;
#endif
}

// ---------------- Phase A: out[b][t][h] = dot(x[b][t][:], W_in[h][:]) -------
// grid 4096 = 256 b x 16 tiles(128 rows), block 256 (4 waves, 32 rows each).
// 16KB x-tile staged coalesced into LDS; per-row reads are b128 broadcasts;
// stores coalesced. Accumulation order identical to all passing kernels.
__global__ __launch_bounds__(256) void ctrnn_xproj(
    const float* __restrict__ x,
    const float* __restrict__ W_in,
    float* __restrict__ out)
{
    __shared__ alignas(16) float xs[128 * Dd];   // 16 KB
    const int tid  = threadIdx.x;
    const int lane = tid & 63;
    const int wave = tid >> 6;
    const int b    = blockIdx.x >> 4;
    const int tile = blockIdx.x & 15;
    const int t0   = tile * 128;

    // coalesced stage: 4096 floats = 1024 float4 = 4 rounds x 256 threads
    const float4* xsrc = reinterpret_cast<const float4*>(
        x + (size_t)b * Tt * Dd + (size_t)t0 * Dd);
    float4* xdst = reinterpret_cast<float4*>(xs);
#pragma unroll
    for (int r = 0; r < 4; ++r) xdst[r * 256 + tid] = xsrc[r * 256 + tid];

    // W row per lane as v2f pairs: w[k] = W_in[lane][2k..2k+1]
    v2f w[16];
    const v2f* wrow = reinterpret_cast<const v2f*>(W_in + lane * Dd);
#pragma unroll
    for (int j = 0; j < 16; ++j) w[j] = wrow[j];

    __syncthreads();

    float* ob = out + (size_t)b * Tt * Hh + (size_t)t0 * Hh;
    const int lt0 = wave * 32;
#pragma unroll 2
    for (int i = 0; i < 32; ++i) {
        const float4* xr = reinterpret_cast<const float4*>(xs + (lt0 + i) * Dd);
        v2f a01 = {0.f, 0.f}, a23 = {0.f, 0.f};
#pragma unroll
        for (int j = 0; j < 8; ++j) {
            const float4 xv = xr[j];
            const v2f x01 = {xv.x, xv.y};
            const v2f x23 = {xv.z, xv.w};
            a01 = vfma2(w[2 * j + 0], x01, a01);   // elements 4j, 4j+1
            a23 = vfma2(w[2 * j + 1], x23, a23);   // elements 4j+2, 4j+3
        }
        ob[(size_t)(lt0 + i) * Hh + lane] = (a01.x + a01.y) + (a23.x + a23.y);
    }
}

// ---------------- Phase B: sequential recurrence, 1 wave per batch ----------
// Hybrid broadcast: cols 0..31 via v_readlane (4cy each, fills the LDS
// latency window), cols 32..63 via ds_read_b128 broadcast of hs[32..63]
// issued at the END of the previous iteration (software pipeline, depth 1).
__global__ __launch_bounds__(64) void ctrnn_recur(
    const float* __restrict__ b_in,
    const float* __restrict__ W_hh,
    const float* __restrict__ b_hh,
    float* __restrict__ out)
{
    const int b    = blockIdx.x;
    const int lane = threadIdx.x;

    __shared__ alignas(16) float hs[Hh];

    // W_hh row of this lane: w4[k].{x,y,z,w} = W_hh[lane][4k..4k+3]
    float4 w4[16];
    const float4* wr = reinterpret_cast<const float4*>(W_hh + lane * Hh);
#pragma unroll
    for (int j = 0; j < 16; ++j) w4[j] = wr[j];

    const float cb = ALPHA * (b_in[lane] + b_hh[lane]);

    float* ob = out + (size_t)b * Tt * Hh + lane;

    float xp[8];
#pragma unroll
    for (int j = 0; j < 8; ++j) xp[j] = ob[(size_t)j * Hh];

    float* op       = ob;                   // store ptr (row t)
    const float* lp = ob + 8 * (size_t)Hh;  // refill ptr (row t+8)

    const float4* h4 = reinterpret_cast<const float4*>(hs);

    // prologue: h_0 = 0; q holds h[32..63] of the upcoming step
    hs[lane] = 0.0f;   // single wave: in-order LDS pipe orders later reads
    float4 q0 = h4[8],  q1 = h4[9],  q2 = h4[10], q3 = h4[11];
    float4 q4 = h4[12], q5 = h4[13], q6 = h4[14], q7 = h4[15];

    float hold = 0.0f;
    for (int t = 0; t < Tt; t += 8) {
#pragma unroll
        for (int j = 0; j < 8; ++j) {
            const int hb = __float_as_int(hold);
            float s0 = 0.f, s1 = 0.f, s2 = 0.f, s3 = 0.f;
            // cols 0..31 via readlane (ascending; fills LDS latency window)
#pragma unroll
            for (int k = 0; k < 8; ++k) {
                const float h0 = __int_as_float(__builtin_amdgcn_readlane(hb, 4 * k + 0));
                const float h1 = __int_as_float(__builtin_amdgcn_readlane(hb, 4 * k + 1));
                const float h2 = __int_as_float(__builtin_amdgcn_readlane(hb, 4 * k + 2));
                const float h3 = __int_as_float(__builtin_amdgcn_readlane(hb, 4 * k + 3));
                s0 = fmaf(w4[k].x, h0, s0);   // col 4k
                s1 = fmaf(w4[k].y, h1, s1);   // col 4k+1
                s2 = fmaf(w4[k].z, h2, s2);   // col 4k+2
                s3 = fmaf(w4[k].w, h3, s3);   // col 4k+3
            }
            // cols 32..63 from q (VGPR fmacs, data pipelined from prev iter)
            s0 = fmaf(w4[ 8].x, q0.x, s0); s1 = fmaf(w4[ 8].y, q0.y, s1);
            s2 = fmaf(w4[ 8].z, q0.z, s2); s3 = fmaf(w4[ 8].w, q0.w, s3);
            s0 = fmaf(w4[ 9].x, q1.x, s0); s1 = fmaf(w4[ 9].y, q1.y, s1);
            s2 = fmaf(w4[ 9].z, q1.z, s2); s3 = fmaf(w4[ 9].w, q1.w, s3);
            s0 = fmaf(w4[10].x, q2.x, s0); s1 = fmaf(w4[10].y, q2.y, s1);
            s2 = fmaf(w4[10].z, q2.z, s2); s3 = fmaf(w4[10].w, q2.w, s3);
            s0 = fmaf(w4[11].x, q3.x, s0); s1 = fmaf(w4[11].y, q3.y, s1);
            s2 = fmaf(w4[11].z, q3.z, s2); s3 = fmaf(w4[11].w, q3.w, s3);
            s0 = fmaf(w4[12].x, q4.x, s0); s1 = fmaf(w4[12].y, q4.y, s1);
            s2 = fmaf(w4[12].z, q4.z, s2); s3 = fmaf(w4[12].w, q4.w, s3);
            s0 = fmaf(w4[13].x, q5.x, s0); s1 = fmaf(w4[13].y, q5.y, s1);
            s2 = fmaf(w4[13].z, q5.z, s2); s3 = fmaf(w4[13].w, q5.w, s3);
            s0 = fmaf(w4[14].x, q6.x, s0); s1 = fmaf(w4[14].y, q6.y, s1);
            s2 = fmaf(w4[14].z, q6.z, s2); s3 = fmaf(w4[14].w, q6.w, s3);
            s0 = fmaf(w4[15].x, q7.x, s0); s1 = fmaf(w4[15].y, q7.y, s1);
            s2 = fmaf(w4[15].z, q7.z, s2); s3 = fmaf(w4[15].w, q7.w, s3);

            const float sum  = ((s0 + s2) + (s1 + s3)) + xp[j];
            const float hnew = fmaxf(fmaf(ALPHA, sum, fmaf(OMA, hold, cb)), 0.0f);

            // publish h_t[32..63] for next iter, then immediately issue the
            // broadcast reads: their ~120cy latency hides under next iter's
            // readlane block. Aliasing (hs[lane] vs hs[32..63]) stops the
            // compiler from reordering read before write; LDS pipe is
            // in-order within a wave (r0-proven).
            hs[lane] = hnew;
            q0 = h4[8];  q1 = h4[9];  q2 = h4[10]; q3 = h4[11];
            q4 = h4[12]; q5 = h4[13]; q6 = h4[14]; q7 = h4[15];

            *op = hnew;                    // overwrite xp row t+j with h
            op += Hh;
            hold = hnew;

            // refill ring 8 ahead (in-bounds past Tt: lands in hlast region,
            // value never consumed)
            xp[j] = *lp;
            lp += Hh;
        }
    }
    // h_last
    out[(size_t)Bb * Tt * Hh + (size_t)b * Hh + lane] = hold;
}

extern "C" void kernel_launch(void* const* d_in, const int* in_sizes, int n_in,
                              void* d_out, int out_size, void* d_ws, size_t ws_size,
                              hipStream_t stream) {
    const float* x    = (const float*)d_in[0];
    // d_in[1] = seq_lengths (int32): forward value is mask-independent.
    const float* W_in = (const float*)d_in[2];
    const float* b_in = (const float*)d_in[3];
    const float* W_hh = (const float*)d_in[4];
    const float* b_hh = (const float*)d_in[5];
    float* out = (float*)d_out;

    ctrnn_xproj<<<dim3(Bb * 16), dim3(256), 0, stream>>>(x, W_in, out);
    ctrnn_recur<<<dim3(Bb), dim3(64), 0, stream>>>(b_in, W_hh, b_hh, out);
}

// Round 6
// 537.707 us; speedup vs baseline: 1.9127x; 1.0640x over previous
//
#include <hip/hip_runtime.h>

// CTRNN forward, B=256 T=2048 D=32 H=64. ALL tensors fp32.
// r9 = r8(572us) with recur changes targeting the ~180cy/step stall:
//  - r8 post-mortem: VALU issue 281cy/step (model-exact); 180cy stall left.
//    Theory: xp ring refill (*lp, reads `out`) vs h store (*op, writes `out`)
//    can alias (same buffer, 8 rows apart) -> compiler orders load after
//    store with a conservative vmcnt wait every step (~store-ack latency).
//  - Fix: xproj writes xp into d_ws; recur reads xp from ws (__restrict__)
//    and writes h to out (__restrict__, distinct). No aliasing, no wait.
//    Runtime fallback to the proven r8 in-place kernel if ws too small.
//  - q-part (cols 32..63): 32 scalar fmac -> 16 v_pk_fma_f32 on adjacent
//    reg pairs (shufflevector), -32cy issue. Per-accumulator order identical:
//    s0: cols 0,4..28 then 32,36..60 (s1/s2/s3 likewise), final
//    ((s0+s2)+(s1+s3))+xp, same hnew formula -> bit-identical, absmax
//    must stay 0.0078125.
//  - sched_barrier(0) pins the q-read issue at iteration end; pre-next
//    fmaf(OMA,h,cb) hoisted into the previous step's shadow.
// xproj: unchanged math (passed), destination is now a parameter.

#define Bb 256
#define Tt 2048
#define Dd 32
#define Hh 64

typedef float v2f __attribute__((ext_vector_type(2)));
typedef float v4f __attribute__((ext_vector_type(4)));

static constexpr float ALPHA = (float)(16.67 / 40.0);
static constexpr float OMA   = 1.0f - ALPHA;

static __device__ inline v2f vfma2(v2f a, v2f b, v2f c) {
#if __has_builtin(__builtin_elementwise_fma)
    return __builtin_elementwise_fma(a, b, c);
#else
    v2f r; r.x = fmaf(a.x, b.x, c.x); r.y = fmaf(a.y, b.y, c.y); return r;
#endif
}

// ---------------- Phase A: xq[b][t][h] = dot(x[b][t][:], W_in[h][:]) -------
// grid 4096 = 256 b x 16 tiles(128 rows), block 256 (4 waves, 32 rows each).
// Math identical to all passing kernels.
__global__ __launch_bounds__(256) void ctrnn_xproj(
    const float* __restrict__ x,
    const float* __restrict__ W_in,
    float* __restrict__ xq)
{
    __shared__ alignas(16) float xs[128 * Dd];   // 16 KB
    const int tid  = threadIdx.x;
    const int lane = tid & 63;
    const int wave = tid >> 6;
    const int b    = blockIdx.x >> 4;
    const int tile = blockIdx.x & 15;
    const int t0   = tile * 128;

    const float4* xsrc = reinterpret_cast<const float4*>(
        x + (size_t)b * Tt * Dd + (size_t)t0 * Dd);
    float4* xdst = reinterpret_cast<float4*>(xs);
#pragma unroll
    for (int r = 0; r < 4; ++r) xdst[r * 256 + tid] = xsrc[r * 256 + tid];

    v2f w[16];
    const v2f* wrow = reinterpret_cast<const v2f*>(W_in + lane * Dd);
#pragma unroll
    for (int j = 0; j < 16; ++j) w[j] = wrow[j];

    __syncthreads();

    float* ob = xq + (size_t)b * Tt * Hh + (size_t)t0 * Hh;
    const int lt0 = wave * 32;
#pragma unroll 2
    for (int i = 0; i < 32; ++i) {
        const float4* xr = reinterpret_cast<const float4*>(xs + (lt0 + i) * Dd);
        v2f a01 = {0.f, 0.f}, a23 = {0.f, 0.f};
#pragma unroll
        for (int j = 0; j < 8; ++j) {
            const float4 xv = xr[j];
            const v2f x01 = {xv.x, xv.y};
            const v2f x23 = {xv.z, xv.w};
            a01 = vfma2(w[2 * j + 0], x01, a01);
            a23 = vfma2(w[2 * j + 1], x23, a23);
        }
        ob[(size_t)(lt0 + i) * Hh + lane] = (a01.x + a01.y) + (a23.x + a23.y);
    }
}

// ---------------- Phase B (ws path): no-alias recur ------------------------
// Hybrid broadcast: cols 0..31 readlane+fmac (fills LDS latency window),
// cols 32..63 via 8x ds_read_b128 of hs[32..63] pipelined 1 iter ahead,
// consumed as v_pk_fma_f32. xp from ws (restrict), h to out (restrict).
__global__ __launch_bounds__(64) void ctrnn_recur_ws(
    const float* __restrict__ b_in,
    const float* __restrict__ W_hh,
    const float* __restrict__ b_hh,
    const float* __restrict__ xq,
    float* __restrict__ out)
{
    const int b    = blockIdx.x;
    const int lane = threadIdx.x;

    __shared__ alignas(16) float hs[Hh];

    // W_hh row of this lane as v4f: w4[k] = W_hh[lane][4k..4k+3]
    v4f w4[16];
    const v4f* wr = reinterpret_cast<const v4f*>(W_hh + lane * Hh);
#pragma unroll
    for (int j = 0; j < 16; ++j) w4[j] = wr[j];

    const float cb = ALPHA * (b_in[lane] + b_hh[lane]);

    const float* xb = xq + (size_t)b * Tt * Hh + lane;
    float*       op = out + (size_t)b * Tt * Hh + lane;

    float xp[8];
#pragma unroll
    for (int j = 0; j < 8; ++j) xp[j] = xb[(size_t)j * Hh];
    const float* lp = xb + 8 * (size_t)Hh;   // refill ptr (row t+8)

    const v4f* h4 = reinterpret_cast<const v4f*>(hs);

    // prologue: h_0 = 0; q holds h[32..63] of the upcoming step
    hs[lane] = 0.0f;   // single wave: in-order LDS pipe orders later reads
    v4f q0 = h4[8],  q1 = h4[9],  q2 = h4[10], q3 = h4[11];
    v4f q4 = h4[12], q5 = h4[13], q6 = h4[14], q7 = h4[15];

    float hold = 0.0f;
    float pre  = cb;              // fmaf(OMA, 0, cb) == cb exactly
    for (int t = 0; t < Tt; t += 8) {
#pragma unroll
        for (int j = 0; j < 8; ++j) {
            const int hb = __float_as_int(hold);
            float s0 = 0.f, s1 = 0.f, s2 = 0.f, s3 = 0.f;
            // cols 0..31 via readlane (ascending; fills LDS latency window)
#pragma unroll
            for (int k = 0; k < 8; ++k) {
                const float h0 = __int_as_float(__builtin_amdgcn_readlane(hb, 4 * k + 0));
                const float h1 = __int_as_float(__builtin_amdgcn_readlane(hb, 4 * k + 1));
                const float h2 = __int_as_float(__builtin_amdgcn_readlane(hb, 4 * k + 2));
                const float h3 = __int_as_float(__builtin_amdgcn_readlane(hb, 4 * k + 3));
                s0 = fmaf(w4[k][0], h0, s0);   // col 4k
                s1 = fmaf(w4[k][1], h1, s1);   // col 4k+1
                s2 = fmaf(w4[k][2], h2, s2);   // col 4k+2
                s3 = fmaf(w4[k][3], h3, s3);   // col 4k+3
            }
            // cols 32..63 from q via pk_fma; per-accumulator order identical
            // to the scalar version (s0: 32,36..60 asc; etc.)
            v2f acc01 = {s0, s1}, acc23 = {s2, s3};
#define QPK(K, Q)                                                              \
            acc01 = vfma2(__builtin_shufflevector(w4[K], w4[K], 0, 1),         \
                          __builtin_shufflevector((Q), (Q), 0, 1), acc01);     \
            acc23 = vfma2(__builtin_shufflevector(w4[K], w4[K], 2, 3),         \
                          __builtin_shufflevector((Q), (Q), 2, 3), acc23);
            QPK( 8, q0) QPK( 9, q1) QPK(10, q2) QPK(11, q3)
            QPK(12, q4) QPK(13, q5) QPK(14, q6) QPK(15, q7)
#undef QPK
            const v2f tt     = acc01 + acc23;           // {s0+s2, s1+s3}
            const float sum  = (tt.x + tt.y) + xp[j];
            const float hnew = fmaxf(fmaf(ALPHA, sum, pre), 0.0f);

            // publish h_t[32..63] for next iter, then immediately issue the
            // broadcast reads; pin their issue point with sched_barrier so
            // their latency hides under the next readlane block.
            hs[lane] = hnew;
            q0 = h4[8];  q1 = h4[9];  q2 = h4[10]; q3 = h4[11];
            q4 = h4[12]; q5 = h4[13]; q6 = h4[14]; q7 = h4[15];
            __builtin_amdgcn_sched_barrier(0);

            *op = hnew;                    // h store (distinct buffer from xq)
            op += Hh;
            hold = hnew;
            pre  = fmaf(OMA, hnew, cb);    // next step's pre, in the shadow

            xp[j] = *lp;                   // refill ring 8 ahead (no alias!)
            lp += Hh;
        }
    }
    out[(size_t)Bb * Tt * Hh + (size_t)b * Hh + lane] = hold;
}

// ---------------- Phase B (fallback): exact r8 in-place kernel -------------
__global__ __launch_bounds__(64) void ctrnn_recur_ip(
    const float* __restrict__ b_in,
    const float* __restrict__ W_hh,
    const float* __restrict__ b_hh,
    float* __restrict__ out)
{
    const int b    = blockIdx.x;
    const int lane = threadIdx.x;

    __shared__ alignas(16) float hs[Hh];

    float4 w4[16];
    const float4* wr = reinterpret_cast<const float4*>(W_hh + lane * Hh);
#pragma unroll
    for (int j = 0; j < 16; ++j) w4[j] = wr[j];

    const float cb = ALPHA * (b_in[lane] + b_hh[lane]);

    float* ob = out + (size_t)b * Tt * Hh + lane;

    float xp[8];
#pragma unroll
    for (int j = 0; j < 8; ++j) xp[j] = ob[(size_t)j * Hh];

    float* op       = ob;
    const float* lp = ob + 8 * (size_t)Hh;

    const float4* h4 = reinterpret_cast<const float4*>(hs);

    hs[lane] = 0.0f;
    float4 q0 = h4[8],  q1 = h4[9],  q2 = h4[10], q3 = h4[11];
    float4 q4 = h4[12], q5 = h4[13], q6 = h4[14], q7 = h4[15];

    float hold = 0.0f;
    for (int t = 0; t < Tt; t += 8) {
#pragma unroll
        for (int j = 0; j < 8; ++j) {
            const int hb = __float_as_int(hold);
            float s0 = 0.f, s1 = 0.f, s2 = 0.f, s3 = 0.f;
#pragma unroll
            for (int k = 0; k < 8; ++k) {
                const float h0 = __int_as_float(__builtin_amdgcn_readlane(hb, 4 * k + 0));
                const float h1 = __int_as_float(__builtin_amdgcn_readlane(hb, 4 * k + 1));
                const float h2 = __int_as_float(__builtin_amdgcn_readlane(hb, 4 * k + 2));
                const float h3 = __int_as_float(__builtin_amdgcn_readlane(hb, 4 * k + 3));
                s0 = fmaf(w4[k].x, h0, s0);
                s1 = fmaf(w4[k].y, h1, s1);
                s2 = fmaf(w4[k].z, h2, s2);
                s3 = fmaf(w4[k].w, h3, s3);
            }
            s0 = fmaf(w4[ 8].x, q0.x, s0); s1 = fmaf(w4[ 8].y, q0.y, s1);
            s2 = fmaf(w4[ 8].z, q0.z, s2); s3 = fmaf(w4[ 8].w, q0.w, s3);
            s0 = fmaf(w4[ 9].x, q1.x, s0); s1 = fmaf(w4[ 9].y, q1.y, s1);
            s2 = fmaf(w4[ 9].z, q1.z, s2); s3 = fmaf(w4[ 9].w, q1.w, s3);
            s0 = fmaf(w4[10].x, q2.x, s0); s1 = fmaf(w4[10].y, q2.y, s1);
            s2 = fmaf(w4[10].z, q2.z, s2); s3 = fmaf(w4[10].w, q2.w, s3);
            s0 = fmaf(w4[11].x, q3.x, s0); s1 = fmaf(w4[11].y, q3.y, s1);
            s2 = fmaf(w4[11].z, q3.z, s2); s3 = fmaf(w4[11].w, q3.w, s3);
            s0 = fmaf(w4[12].x, q4.x, s0); s1 = fmaf(w4[12].y, q4.y, s1);
            s2 = fmaf(w4[12].z, q4.z, s2); s3 = fmaf(w4[12].w, q4.w, s3);
            s0 = fmaf(w4[13].x, q5.x, s0); s1 = fmaf(w4[13].y, q5.y, s1);
            s2 = fmaf(w4[13].z, q5.z, s2); s3 = fmaf(w4[13].w, q5.w, s3);
            s0 = fmaf(w4[14].x, q6.x, s0); s1 = fmaf(w4[14].y, q6.y, s1);
            s2 = fmaf(w4[14].z, q6.z, s2); s3 = fmaf(w4[14].w, q6.w, s3);
            s0 = fmaf(w4[15].x, q7.x, s0); s1 = fmaf(w4[15].y, q7.y, s1);
            s2 = fmaf(w4[15].z, q7.z, s2); s3 = fmaf(w4[15].w, q7.w, s3);

            const float sum  = ((s0 + s2) + (s1 + s3)) + xp[j];
            const float hnew = fmaxf(fmaf(ALPHA, sum, fmaf(OMA, hold, cb)), 0.0f);

            hs[lane] = hnew;
            q0 = h4[8];  q1 = h4[9];  q2 = h4[10]; q3 = h4[11];
            q4 = h4[12]; q5 = h4[13]; q6 = h4[14]; q7 = h4[15];

            *op = hnew;
            op += Hh;
            hold = hnew;

            xp[j] = *lp;
            lp += Hh;
        }
    }
    out[(size_t)Bb * Tt * Hh + (size_t)b * Hh + lane] = hold;
}

extern "C" void kernel_launch(void* const* d_in, const int* in_sizes, int n_in,
                              void* d_out, int out_size, void* d_ws, size_t ws_size,
                              hipStream_t stream) {
    const float* x    = (const float*)d_in[0];
    // d_in[1] = seq_lengths (int32): forward value is mask-independent.
    const float* W_in = (const float*)d_in[2];
    const float* b_in = (const float*)d_in[3];
    const float* W_hh = (const float*)d_in[4];
    const float* b_hh = (const float*)d_in[5];
    float* out = (float*)d_out;

    const size_t need = ((size_t)Bb * Tt + 16) * (size_t)Hh * sizeof(float);
    if (d_ws != nullptr && ws_size >= need) {
        float* xq = (float*)d_ws;
        ctrnn_xproj<<<dim3(Bb * 16), dim3(256), 0, stream>>>(x, W_in, xq);
        ctrnn_recur_ws<<<dim3(Bb), dim3(64), 0, stream>>>(b_in, W_hh, b_hh, xq, out);
    } else {
        ctrnn_xproj<<<dim3(Bb * 16), dim3(256), 0, stream>>>(x, W_in, out);
        ctrnn_recur_ip<<<dim3(Bb), dim3(64), 0, stream>>>(b_in, W_hh, b_hh, out);
    }
}